// Round 2
// baseline (878.596 us; speedup 1.0000x reference)
//
#include <hip/hip_runtime.h>

typedef unsigned short u16;
typedef unsigned int   u32;
typedef __attribute__((ext_vector_type(8))) __bf16 bf16x8;
typedef __attribute__((ext_vector_type(4))) float   f32x4;

// ---------------- dims ----------------
#define NT   16384      // tokens = 4*4096
#define DD   1024
#define FFD  4096

// ---------------- ws layout (bytes), total ~152 MB ----------------
#define SREG  ((size_t)33554432)            // 32MB = 16384*1024*2
#define S1O   ((size_t)0)
#define S2O   (SREG)
#define S3O   (2*SREG)
#define S4O   (3*SREG)
#define O_WQ  (4*SREG)                      // 134,217,728
#define O_WK  (O_WQ + (size_t)2097152)
#define O_W1  (O_WK + (size_t)2097152)
#define O_W2  (O_W1 + (size_t)8388608)
#define O_FWD (O_W2 + (size_t)8388608)
#define O_INV (O_FWD + (size_t)2097152)
#define O_SF  (O_INV + (size_t)2097152)
// end = O_SF + 16384 = 159,399,936 bytes

// ---------------- helpers ----------------
__device__ __forceinline__ float b2f(u16 h) {
    u32 u = ((u32)h) << 16;
    return __uint_as_float(u);
}
__device__ __forceinline__ u16 f2b(float f) {  // RNE
    u32 u = __float_as_uint(f);
    u32 r = (u + 0x7FFFu + ((u >> 16) & 1u)) >> 16;
    return (u16)r;
}

__device__ __forceinline__ void ld16(const u16* g, u16* l) {
    __builtin_amdgcn_global_load_lds(
        (const __attribute__((address_space(1))) void*)g,
        (__attribute__((address_space(3))) void*)l, 16, 0, 0);
}

__device__ __forceinline__ void block_red2(float& a, float& b, float* red, int tid) {
#pragma unroll
    for (int off = 32; off; off >>= 1) {
        a += __shfl_down(a, off, 64);
        b += __shfl_down(b, off, 64);
    }
    int w = tid >> 6;
    if ((tid & 63) == 0) { red[w] = a; red[4 + w] = b; }
    __syncthreads();
    a = red[0] + red[1] + red[2] + red[3];
    b = red[4] + red[5] + red[6] + red[7];
}

// ---------------- small utility kernels ----------------
__global__ void zero_sf_k(float* __restrict__ Sf) {
    int i = blockIdx.x * 256 + threadIdx.x;
    if (i < 4096) Sf[i] = 0.f;
}

__global__ void cast_f32_bf16_k(const float* __restrict__ s, u16* __restrict__ d, int n4) {
    int i = blockIdx.x * 256 + threadIdx.x;
    if (i < n4) {
        float4 v = ((const float4*)s)[i];
        ushort4 o;
        o.x = f2b(v.x); o.y = f2b(v.y); o.z = f2b(v.z); o.w = f2b(v.w);
        ((ushort4*)d)[i] = o;
    }
}

// ---------------- packed-spectrum DFT matrices (bf16) ----------------
__global__ void gen_fwd_k(u16* __restrict__ Fwd) {
    int idx = blockIdx.x * 256 + threadIdx.x;   // 1024*1024
    int n = idx >> 10, k = idx & 1023;
    int f  = (n == 0) ? 0 : ((n & 1) ? ((n + 1) >> 1) : (n >> 1));
    bool re = (n == 0) || (n & 1);
    int r = (f * k) & 1023;
    float ang = (float)r * 6.1359233e-3f;   // 2*pi/1024
    float v = re ? __cosf(ang) : -__sinf(ang);
    Fwd[idx] = f2b(v);
}
__global__ void gen_inv_k(u16* __restrict__ Inv) {
    int idx = blockIdx.x * 256 + threadIdx.x;   // 1024*1024
    int d = idx >> 10, n = idx & 1023;
    int f  = (n == 0) ? 0 : ((n & 1) ? ((n + 1) >> 1) : (n >> 1));
    bool re = (n == 0) || (n & 1);
    int r = (f * d) & 1023;
    float ang = (float)r * 6.1359233e-3f;
    float c = (f == 0 || f == 512) ? (1.0f / 1024.0f) : (2.0f / 1024.0f);
    float v = re ? c * __cosf(ang) : -c * __sinf(ang);
    Inv[idx] = f2b(v);
}

// ---------------- GEMM: C[m,n] = sum_k A[m,k]*B[n,k] ----------------
// 256x256 tile, BK=64, 8 waves (2Mx4N), 64 KiB STATIC LDS single-buffered.
// 4-phase schedule: next tile staged into LDS regions as they go dead
// (A band0 after P1, B after P2, A band1 after P3); one s_barrier per
// phase; single vmcnt(0) per K-tile at P4-end (loads issued 1-3 phases
// earlier so latency hides under MFMA). setprio(1) around MFMA clusters.
// XOR-chunk swizzle: LDS slot (row, c) holds global chunk c^(row&7),
// staged by pre-swizzling each lane's GLOBAL chunk (global_load_lds's
// lane->slot map stays linear), read back with the same XOR.
#define BM 256
#define BN 256
#define BK 64
#define EPI_BF16            0  // bf16 store
#define EPI_BIAS_BF16       1  // bf16 store, + bias[n]
#define EPI_BIAS_RELU_BF16  2  // bf16 store, + bias[n], relu
#define EPI_BIAS_ADDB_F32   3  // f32 store,  + bias[n] + bf16 residual addp16[off]
#define EPI_ADD_F32         4  // f32 store,  + existing f32 Cout[off]

#define MFMA16 __builtin_amdgcn_mfma_f32_16x16x32_bf16
#define BARRIER()    asm volatile("s_barrier" ::: "memory")
#define WAIT_LGKM0() asm volatile("s_waitcnt lgkmcnt(0)" ::: "memory")
#define WAIT_VM0()   asm volatile("s_waitcnt vmcnt(0)" ::: "memory")

template <int EPI>
__global__ __launch_bounds__(512, 2) void gemm_bt_k(
    const u16* __restrict__ A, const u16* __restrict__ B, void* __restrict__ Cout,
    const float* __restrict__ bias, const u16* __restrict__ addp16,
    int K, int lda, int ldb, int ldc)
{
    __shared__ __align__(16) u16 As[BM * BK];   // 32 KiB
    __shared__ __align__(16) u16 Bs[BN * BK];   // 32 KiB
    const int tid = threadIdx.x;

    // XCD-aware swizzle: blocks with id%8==c (one XCD) cover a CONTIGUOUS
    // m-band x all n-tiles -> per-XCD A footprint drops 8x.
    int m0, n0;
    {
        const int id = blockIdx.y * gridDim.x + blockIdx.x;
        const int nb = gridDim.x * gridDim.y;
        if ((nb & 7) == 0) {
            const int per = nb >> 3;
            const int t = (id & 7) * per + (id >> 3);
            n0 = (t % gridDim.x) * BN;
            m0 = (t / gridDim.x) * BM;
        } else {
            n0 = blockIdx.x * BN;
            m0 = blockIdx.y * BM;
        }
    }

    const int wid = tid >> 6, l = tid & 63;
    const int wm = (wid >> 2) << 7;        // 0 or 128
    const int wn = (wid & 3) << 6;         // 0,64,128,192
    const int tm = l & 15, quad = l >> 4;
    // read-side swizzled chunk offsets (u16 elems) for k-chunk 0 / 1
    const int cx0 = ((quad ^ (tm & 7)) << 3);
    const int cx1 = (((quad + 4) ^ (tm & 7)) << 3);

    f32x4 acc[8][4] = {};

    // staging: thread covers row srow (+64/round h), swizzled global chunk
    const int srow = tid >> 3;
    const int scol = ((tid & 7) ^ (srow & 7)) << 3;
    const u16* Ag = A + (size_t)(m0 + srow) * lda + scol;
    const u16* Bg = B + (size_t)(n0 + srow) * ldb + scol;
    u16* Asl = As + tid * 8;
    u16* Bsl = Bs + tid * 8;
    const size_t a64 = (size_t)64 * lda, b64 = (size_t)64 * ldb;

    const u16* ArA = As + (wm + tm) * BK;
    const u16* ArB = Bs + (wn + tm) * BK;

    const int ntk = K >> 6;   // K-tiles

    // prologue: stage tile 0 fully, drain, barrier
#pragma unroll
    for (int h = 0; h < 4; ++h) {
        ld16(Ag + (size_t)h * a64, Asl + h * 4096);
        ld16(Bg + (size_t)h * b64, Bsl + h * 4096);
    }
    WAIT_VM0();
    BARRIER();

    for (int t = 0; t < ntk; ++t) {
        // prefetch K-offset (tail: restage current tile = identical bytes, benign)
        const size_t kn = (size_t)(((t + 1 < ntk) ? (t + 1) : t) << 6);
        bf16x8 a[4][2], bA[2][2], bB[2][2];

        // ---- P1: A band0 x B cols 0-1 -> acc[0..3][0..1] ----
#pragma unroll
        for (int i = 0; i < 4; ++i) {
            a[i][0] = *(const bf16x8*)(const void*)(ArA + i * 1024 + cx0);
            a[i][1] = *(const bf16x8*)(const void*)(ArA + i * 1024 + cx1);
        }
#pragma unroll
        for (int j = 0; j < 2; ++j) {
            bA[j][0] = *(const bf16x8*)(const void*)(ArB + j * 1024 + cx0);
            bA[j][1] = *(const bf16x8*)(const void*)(ArB + j * 1024 + cx1);
        }
        WAIT_LGKM0();
        __builtin_amdgcn_s_setprio(1);
#pragma unroll
        for (int i = 0; i < 4; ++i)
#pragma unroll
            for (int j = 0; j < 2; ++j) {
                acc[i][j] = MFMA16(a[i][0], bA[j][0], acc[i][j], 0, 0, 0);
                acc[i][j] = MFMA16(a[i][1], bA[j][1], acc[i][j], 0, 0, 0);
            }
        __builtin_amdgcn_s_setprio(0);
        BARRIER();   // A band0 (rows 0-63,128-191) + B half1 now dead

        // ---- P2: stage A(t+1) rounds 0,2; B cols 2-3 -> acc[0..3][2..3] ----
        ld16(Ag + kn,                 Asl);
        ld16(Ag + kn + 2 * a64,       Asl + 2 * 4096);
#pragma unroll
        for (int j = 0; j < 2; ++j) {
            bB[j][0] = *(const bf16x8*)(const void*)(ArB + (2 + j) * 1024 + cx0);
            bB[j][1] = *(const bf16x8*)(const void*)(ArB + (2 + j) * 1024 + cx1);
        }
        WAIT_LGKM0();
        __builtin_amdgcn_s_setprio(1);
#pragma unroll
        for (int i = 0; i < 4; ++i)
#pragma unroll
            for (int j = 0; j < 2; ++j) {
                acc[i][2 + j] = MFMA16(a[i][0], bB[j][0], acc[i][2 + j], 0, 0, 0);
                acc[i][2 + j] = MFMA16(a[i][1], bB[j][1], acc[i][2 + j], 0, 0, 0);
            }
        __builtin_amdgcn_s_setprio(0);
        BARRIER();   // B half2 now dead -> all of B dead

        // ---- P3: stage B(t+1) fully; A band1 x B cols 2-3 ----
#pragma unroll
        for (int h = 0; h < 4; ++h)
            ld16(Bg + kn + (size_t)h * b64, Bsl + h * 4096);
#pragma unroll
        for (int i = 0; i < 4; ++i) {
            a[i][0] = *(const bf16x8*)(const void*)(ArA + (4 + i) * 1024 + cx0);
            a[i][1] = *(const bf16x8*)(const void*)(ArA + (4 + i) * 1024 + cx1);
        }
        WAIT_LGKM0();
        __builtin_amdgcn_s_setprio(1);
#pragma unroll
        for (int i = 0; i < 4; ++i)
#pragma unroll
            for (int j = 0; j < 2; ++j) {
                acc[4 + i][2 + j] = MFMA16(a[i][0], bB[j][0], acc[4 + i][2 + j], 0, 0, 0);
                acc[4 + i][2 + j] = MFMA16(a[i][1], bB[j][1], acc[4 + i][2 + j], 0, 0, 0);
            }
        __builtin_amdgcn_s_setprio(0);
        BARRIER();   // A band1 now dead

        // ---- P4: stage A(t+1) rounds 1,3; A band1(reg) x B cols 0-1(reg) ----
        ld16(Ag + kn + a64,           Asl + 4096);
        ld16(Ag + kn + 3 * a64,       Asl + 3 * 4096);
        __builtin_amdgcn_s_setprio(1);
#pragma unroll
        for (int i = 0; i < 4; ++i)
#pragma unroll
            for (int j = 0; j < 2; ++j) {
                acc[4 + i][j] = MFMA16(a[i][0], bA[j][0], acc[4 + i][j], 0, 0, 0);
                acc[4 + i][j] = MFMA16(a[i][1], bA[j][1], acc[4 + i][j], 0, 0, 0);
            }
        __builtin_amdgcn_s_setprio(0);
        WAIT_VM0();  // all 8 stage loads of tile t+1 landed
        BARRIER();
    }

    // C/D layout: col=lane&15, row=quad*4+reg (m89/m91-verified)
#pragma unroll
    for (int i = 0; i < 8; ++i) {
        const int gmb = m0 + wm + i * 16 + (quad << 2);
#pragma unroll
        for (int j = 0; j < 4; ++j) {
            const int gn = n0 + wn + j * 16 + tm;
            float bv = 0.f;
            if (EPI == EPI_BIAS_BF16 || EPI == EPI_BIAS_RELU_BF16 || EPI == EPI_BIAS_ADDB_F32)
                bv = bias[gn];
#pragma unroll
            for (int r = 0; r < 4; ++r) {
                size_t off = (size_t)(gmb + r) * ldc + gn;
                float v = acc[i][j][r] + bv;
                if (EPI == EPI_BIAS_ADDB_F32) v += b2f(addp16[off]);
                if (EPI == EPI_ADD_F32)       v += ((const float*)Cout)[off];
                if (EPI == EPI_BIAS_RELU_BF16) v = fmaxf(v, 0.f);
                if (EPI == EPI_BF16 || EPI == EPI_BIAS_BF16 || EPI == EPI_BIAS_RELU_BF16)
                    ((u16*)Cout)[off] = f2b(v);
                else
                    ((float*)Cout)[off] = v;
            }
        }
    }
}

// ---------------- LayerNorm bf16 -> bf16 (may be in-place) ----------------
__global__ void ln_bf16_k(const u16* __restrict__ src, u16* __restrict__ dst,
                          const float* __restrict__ g, const float* __restrict__ be) {
    __shared__ float red[8];
    const int t = blockIdx.x, tid = threadIdx.x;
    ushort4 h = ((const ushort4*)(src + (size_t)t * DD))[tid];
    float4 v = { b2f(h.x), b2f(h.y), b2f(h.z), b2f(h.w) };
    float s  = v.x + v.y + v.z + v.w;
    float ss = v.x * v.x + v.y * v.y + v.z * v.z + v.w * v.w;
    block_red2(s, ss, red, tid);
    float mean = s * (1.f / 1024.f);
    float inv  = 1.0f / sqrtf(ss * (1.f / 1024.f) - mean * mean + 1e-5f);
    float4 gv = ((const float4*)g)[tid];
    float4 bv = ((const float4*)be)[tid];
    ushort4 o;
    o.x = f2b((v.x - mean) * inv * gv.x + bv.x);
    o.y = f2b((v.y - mean) * inv * gv.y + bv.y);
    o.z = f2b((v.z - mean) * inv * gv.z + bv.z);
    o.w = f2b((v.w - mean) * inv * gv.w + bv.w);
    ((ushort4*)(dst + (size_t)t * DD))[tid] = o;
}

// ---------------- final LN in place on d_out (f32) ----------------
__global__ void ln_out_k(float* __restrict__ io, const float* __restrict__ g,
                         const float* __restrict__ be) {
    __shared__ float red[8];
    const int t = blockIdx.x, tid = threadIdx.x;
    float4 v = ((const float4*)(io + (size_t)t * DD))[tid];
    float s  = v.x + v.y + v.z + v.w;
    float ss = v.x * v.x + v.y * v.y + v.z * v.z + v.w * v.w;
    block_red2(s, ss, red, tid);
    float mean = s * (1.f / 1024.f);
    float inv  = 1.0f / sqrtf(ss * (1.f / 1024.f) - mean * mean + 1e-5f);
    float4 gv = ((const float4*)g)[tid];
    float4 bv = ((const float4*)be)[tid];
    float4 o;
    o.x = (v.x - mean) * inv * gv.x + bv.x;
    o.y = (v.y - mean) * inv * gv.y + bv.y;
    o.z = (v.z - mean) * inv * gv.z + bv.z;
    o.w = (v.w - mean) * inv * gv.w + bv.w;
    ((float4*)(io + (size_t)t * DD))[tid] = o;
}

// ---------------- pw1: Sf[b] += Kf .* Xf  (packed spectra) ----------------
#define PW1_TOK 16
__global__ void pw1_k(const u16* __restrict__ FTx, const u16* __restrict__ FTk,
                      float* __restrict__ Sf) {
    const int tid = threadIdx.x;
    const int t0 = blockIdx.x * PW1_TOK;
    const int b = t0 >> 12;
    float a0 = 0.f;
    float ar1 = 0.f, ai1 = 0.f;
    float ar2 = 0.f, ai2 = 0.f;
    const int f1 = tid + 1, f2 = tid + 257;
    for (int it = 0; it < PW1_TOK; ++it) {
        const size_t ro = (size_t)(t0 + it) * DD;
        const u16* rx = FTx + ro;
        const u16* rk = FTk + ro;
        if (tid == 0) a0 += b2f(rk[0]) * b2f(rx[0]);
        {
            float xr = b2f(rx[2 * f1 - 1]), xi = b2f(rx[2 * f1]);
            float kr = b2f(rk[2 * f1 - 1]), ki = b2f(rk[2 * f1]);
            ar1 += kr * xr - ki * xi;
            ai1 += kr * xi + ki * xr;
        }
        if (f2 < 512) {
            float xr = b2f(rx[2 * f2 - 1]), xi = b2f(rx[2 * f2]);
            float kr = b2f(rk[2 * f2 - 1]), ki = b2f(rk[2 * f2]);
            ar2 += kr * xr - ki * xi;
            ai2 += kr * xi + ki * xr;
        } else {
            ar2 += b2f(rk[1023]) * b2f(rx[1023]);
        }
    }
    float* sb = Sf + (size_t)b * DD;
    if (tid == 0) atomicAdd(&sb[0], a0);
    atomicAdd(&sb[2 * f1 - 1], ar1);
    atomicAdd(&sb[2 * f1],     ai1);
    if (f2 < 512) {
        atomicAdd(&sb[2 * f2 - 1], ar2);
        atomicAdd(&sb[2 * f2],     ai2);
    } else {
        atomicAdd(&sb[1023], ar2);
    }
}

// ---------------- pw2: G = Xf + Kf.*Xf + Sf.*conj(Qf), in-place over FTx ----------------
__global__ void pw2_k(u16* __restrict__ FTx, const u16* __restrict__ FTk,
                      const u16* __restrict__ FTq, const float* __restrict__ Sf) {
    const int t = blockIdx.x, tid = threadIdx.x;
    const int b = t >> 12;
    const size_t ro = (size_t)t * DD;
    u16* rx = FTx + ro;
    const u16* rk = FTk + ro;
    const u16* rq = FTq + ro;
    const float* sb = Sf + (size_t)b * DD;
    const int f1 = tid + 1, f2 = tid + 257;
    if (tid == 0) {
        float x = b2f(rx[0]), k = b2f(rk[0]), q = b2f(rq[0]);
        rx[0] = f2b(x + k * x + sb[0] * q);
    }
    {
        float xr = b2f(rx[2 * f1 - 1]), xi = b2f(rx[2 * f1]);
        float kr = b2f(rk[2 * f1 - 1]), ki = b2f(rk[2 * f1]);
        float qr = b2f(rq[2 * f1 - 1]), qi = b2f(rq[2 * f1]);
        float sr = sb[2 * f1 - 1], si = sb[2 * f1];
        rx[2 * f1 - 1] = f2b(xr + (kr * xr - ki * xi) + (sr * qr + si * qi));
        rx[2 * f1]     = f2b(xi + (kr * xi + ki * xr) + (si * qr - sr * qi));
    }
    if (f2 < 512) {
        float xr = b2f(rx[2 * f2 - 1]), xi = b2f(rx[2 * f2]);
        float kr = b2f(rk[2 * f2 - 1]), ki = b2f(rk[2 * f2]);
        float qr = b2f(rq[2 * f2 - 1]), qi = b2f(rq[2 * f2]);
        float sr = sb[2 * f2 - 1], si = sb[2 * f2];
        rx[2 * f2 - 1] = f2b(xr + (kr * xr - ki * xi) + (sr * qr + si * qi));
        rx[2 * f2]     = f2b(xi + (kr * xi + ki * xr) + (si * qr - sr * qi));
    } else {
        float x = b2f(rx[1023]), k = b2f(rk[1023]), q = b2f(rq[1023]);
        rx[1023] = f2b(x + k * x + sb[1023] * q);
    }
}

// ---------------- launch ----------------
extern "C" void kernel_launch(void* const* d_in, const int* in_sizes, int n_in,
                              void* d_out, int out_size, void* d_ws, size_t ws_size,
                              hipStream_t stream) {
    const float* x     = (const float*)d_in[0];
    const float* Wq    = (const float*)d_in[1];
    const float* bq    = (const float*)d_in[2];
    const float* gq    = (const float*)d_in[3];
    const float* betaq = (const float*)d_in[4];
    const float* Wk    = (const float*)d_in[5];
    const float* bk    = (const float*)d_in[6];
    const float* gk    = (const float*)d_in[7];
    const float* betak = (const float*)d_in[8];
    const float* g0    = (const float*)d_in[9];
    const float* beta0 = (const float*)d_in[10];
    const float* W1    = (const float*)d_in[11];
    const float* b1    = (const float*)d_in[12];
    const float* W2    = (const float*)d_in[13];
    const float* b2    = (const float*)d_in[14];
    const float* g1    = (const float*)d_in[15];
    const float* beta1 = (const float*)d_in[16];

    char* ws = (char*)d_ws;
    u16* S1 = (u16*)(ws + S1O);   // xb16 -> FTk -> x1b
    u16* S2 = (u16*)(ws + S2O);   // qb -> T
    u16* S3 = (u16*)(ws + S3O);   // kb -> FTq -> H chunk
    u16* S4 = (u16*)(ws + S4O);   // FTx -> G -> H chunk
    u16* wq16 = (u16*)(ws + O_WQ);
    u16* wk16 = (u16*)(ws + O_WK);
    u16* w116 = (u16*)(ws + O_W1);
    u16* w216 = (u16*)(ws + O_W2);
    u16* fwdP = (u16*)(ws + O_FWD);
    u16* invP = (u16*)(ws + O_INV);
    float* Sf = (float*)(ws + O_SF);
    float* out = (float*)d_out;

    // consts
    zero_sf_k<<<16, 256, 0, stream>>>(Sf);
    cast_f32_bf16_k<<<16384, 256, 0, stream>>>(x, S1, 4194304);
    cast_f32_bf16_k<<<1024, 256, 0, stream>>>(Wq, wq16, 262144);
    cast_f32_bf16_k<<<1024, 256, 0, stream>>>(Wk, wk16, 262144);
    cast_f32_bf16_k<<<4096, 256, 0, stream>>>(W1, w116, 1048576);
    cast_f32_bf16_k<<<4096, 256, 0, stream>>>(W2, w216, 1048576);
    gen_fwd_k<<<4096, 256, 0, stream>>>(fwdP);
    gen_inv_k<<<4096, 256, 0, stream>>>(invP);

    // projections (bias in epilogue, bf16 out), then LN in-place
    gemm_bt_k<EPI_BIAS_BF16><<<dim3(4, 64), 512, 0, stream>>>(S1, wq16, S2, bq, nullptr, 1024, 1024, 1024, 1024);
    gemm_bt_k<EPI_BIAS_BF16><<<dim3(4, 64), 512, 0, stream>>>(S1, wk16, S3, bk, nullptr, 1024, 1024, 1024, 1024);
    ln_bf16_k<<<NT, 256, 0, stream>>>(S2, S2, gq, betaq);
    ln_bf16_k<<<NT, 256, 0, stream>>>(S3, S3, gk, betak);

    // forward DFTs (packed spectra)
    gemm_bt_k<EPI_BF16><<<dim3(4, 64), 512, 0, stream>>>(S1, fwdP, S4, nullptr, nullptr, 1024, 1024, 1024, 1024); // FTx
    gemm_bt_k<EPI_BF16><<<dim3(4, 64), 512, 0, stream>>>(S3, fwdP, S1, nullptr, nullptr, 1024, 1024, 1024, 1024); // FTk
    gemm_bt_k<EPI_BF16><<<dim3(4, 64), 512, 0, stream>>>(S2, fwdP, S3, nullptr, nullptr, 1024, 1024, 1024, 1024); // FTq

    // freq-domain pointwise
    pw1_k<<<NT / PW1_TOK, 256, 0, stream>>>(S4, S1, Sf);
    pw2_k<<<NT, 256, 0, stream>>>(S4, S1, S3, Sf);   // G in-place over FTx (S4)

    // inverse DFT: T = G @ Inv^T (bf16)
    gemm_bt_k<EPI_BF16><<<dim3(4, 64), 512, 0, stream>>>(S4, invP, S2, nullptr, nullptr, 1024, 1024, 1024, 1024);

    // x1 = LN(T) -> bf16
    ln_bf16_k<<<NT, 256, 0, stream>>>(S2, S1, g0, beta0);

    // FFN in two F-chunks of 2048; H chunk lives in S3..S4 (64MB)
    gemm_bt_k<EPI_BIAS_RELU_BF16><<<dim3(8, 64), 512, 0, stream>>>(S1, w116, S3, b1, nullptr, 1024, 1024, 1024, 2048);
    gemm_bt_k<EPI_BIAS_ADDB_F32><<<dim3(4, 64), 512, 0, stream>>>(S3, w216, out, b2, S1, 2048, 2048, 4096, 1024);
    gemm_bt_k<EPI_BIAS_RELU_BF16><<<dim3(8, 64), 512, 0, stream>>>(S1, w116 + (size_t)2048 * 1024, S3, b1 + 2048, nullptr, 1024, 1024, 1024, 2048);
    gemm_bt_k<EPI_ADD_F32><<<dim3(4, 64), 512, 0, stream>>>(S3, w216 + 2048, out, nullptr, nullptr, 2048, 2048, 4096, 1024);

    // final LN in place
    ln_out_k<<<NT, 256, 0, stream>>>(out, g1, beta1);

    (void)in_sizes; (void)n_in; (void)out_size; (void)ws_size;
}

// Round 3
// 843.059 us; speedup vs baseline: 1.0422x; 1.0422x over previous
//
#include <hip/hip_runtime.h>

typedef unsigned short u16;
typedef unsigned int   u32;
typedef __attribute__((ext_vector_type(8))) __bf16 bf16x8;
typedef __attribute__((ext_vector_type(4))) float   f32x4;

// ---------------- dims ----------------
#define NT   16384      // tokens = 4*4096
#define DD   1024
#define FFD  4096

// ---------------- ws layout (bytes), total ~152 MB ----------------
#define SREG  ((size_t)33554432)            // 32MB = 16384*1024*2
#define S1O   ((size_t)0)
#define S2O   (SREG)
#define S3O   (2*SREG)
#define S4O   (3*SREG)
#define O_WQ  (4*SREG)                      // 134,217,728
#define O_WK  (O_WQ + (size_t)2097152)
#define O_W1  (O_WK + (size_t)2097152)
#define O_W2  (O_W1 + (size_t)8388608)
#define O_FWD (O_W2 + (size_t)8388608)
#define O_INV (O_FWD + (size_t)2097152)
#define O_SF  (O_INV + (size_t)2097152)
// end = O_SF + 16384 = 159,399,936 bytes

// ---------------- helpers ----------------
__device__ __forceinline__ float b2f(u16 h) {
    u32 u = ((u32)h) << 16;
    return __uint_as_float(u);
}
__device__ __forceinline__ u16 f2b(float f) {  // RNE
    u32 u = __float_as_uint(f);
    u32 r = (u + 0x7FFFu + ((u >> 16) & 1u)) >> 16;
    return (u16)r;
}

__device__ __forceinline__ void ld16(const u16* g, u16* l) {
    __builtin_amdgcn_global_load_lds(
        (const __attribute__((address_space(1))) void*)g,
        (__attribute__((address_space(3))) void*)l, 16, 0, 0);
}

__device__ __forceinline__ void block_red2(float& a, float& b, float* red, int tid) {
#pragma unroll
    for (int off = 32; off; off >>= 1) {
        a += __shfl_down(a, off, 64);
        b += __shfl_down(b, off, 64);
    }
    int w = tid >> 6;
    if ((tid & 63) == 0) { red[w] = a; red[4 + w] = b; }
    __syncthreads();
    a = red[0] + red[1] + red[2] + red[3];
    b = red[4] + red[5] + red[6] + red[7];
}

// ---------------- small utility kernels ----------------
__global__ void zero_sf_k(float* __restrict__ Sf) {
    int i = blockIdx.x * 256 + threadIdx.x;
    if (i < 4096) Sf[i] = 0.f;
}

__global__ void cast_f32_bf16_k(const float* __restrict__ s, u16* __restrict__ d, int n4) {
    int i = blockIdx.x * 256 + threadIdx.x;
    if (i < n4) {
        float4 v = ((const float4*)s)[i];
        ushort4 o;
        o.x = f2b(v.x); o.y = f2b(v.y); o.z = f2b(v.z); o.w = f2b(v.w);
        ((ushort4*)d)[i] = o;
    }
}

// ---------------- packed-spectrum DFT matrices (bf16) ----------------
__global__ void gen_fwd_k(u16* __restrict__ Fwd) {
    int idx = blockIdx.x * 256 + threadIdx.x;   // 1024*1024
    int n = idx >> 10, k = idx & 1023;
    int f  = (n == 0) ? 0 : ((n & 1) ? ((n + 1) >> 1) : (n >> 1));
    bool re = (n == 0) || (n & 1);
    int r = (f * k) & 1023;
    float ang = (float)r * 6.1359233e-3f;   // 2*pi/1024
    float v = re ? __cosf(ang) : -__sinf(ang);
    Fwd[idx] = f2b(v);
}
__global__ void gen_inv_k(u16* __restrict__ Inv) {
    int idx = blockIdx.x * 256 + threadIdx.x;   // 1024*1024
    int d = idx >> 10, n = idx & 1023;
    int f  = (n == 0) ? 0 : ((n & 1) ? ((n + 1) >> 1) : (n >> 1));
    bool re = (n == 0) || (n & 1);
    int r = (f * d) & 1023;
    float ang = (float)r * 6.1359233e-3f;
    float c = (f == 0 || f == 512) ? (1.0f / 1024.0f) : (2.0f / 1024.0f);
    float v = re ? c * __cosf(ang) : -c * __sinf(ang);
    Inv[idx] = f2b(v);
}

// ---------------- GEMM: C[m,n] = sum_k A[m,k]*B[n,k] ----------------
// 256x256 tile, BK=32, 8 waves (2Mx4N), 64 KiB static LDS, TRUE
// double-buffer with 2-deep prefetch and COUNTED vmcnt (never 0 in loop):
//   per K-tile t:  ds_read(buf t) -> lgkmcnt(0) -> barrier ->
//                  stage tile t+2 into buf(t) -> 32 MFMA (prio 1) ->
//                  vmcnt(4)  [t+1's loads landed; t+2's stay in flight] ->
//                  barrier
// Every stage load gets ~1.5 tiles of MFMA to land (L2-resident operands).
// XOR swizzle for the 64B-row geometry: LDS slot (row,c) holds global
// chunk c ^ ((row>>1)&3); read offset collapses to per-lane constant
// cx = (quad ^ ((tm>>1)&3))*8 -> 2 lanes/bank on ds_read_b128 (free).
#define BM 256
#define BN 256
#define EPI_BF16            0  // bf16 store
#define EPI_BIAS_BF16       1  // bf16 store, + bias[n]
#define EPI_BIAS_RELU_BF16  2  // bf16 store, + bias[n], relu
#define EPI_BIAS_ADDB_F32   3  // f32 store,  + bias[n] + bf16 residual addp16[off]
#define EPI_ADD_F32         4  // f32 store,  + existing f32 Cout[off]

#define MFMA16 __builtin_amdgcn_mfma_f32_16x16x32_bf16
#define BARRIER()    asm volatile("s_barrier" ::: "memory")
#define WAIT_LGKM0() asm volatile("s_waitcnt lgkmcnt(0)" ::: "memory")
#define WAIT_VM4()   asm volatile("s_waitcnt vmcnt(4)" ::: "memory")
#define WAIT_VM0()   asm volatile("s_waitcnt vmcnt(0)" ::: "memory")

// stage K-tile at col k0 of A and B into LDS buffer b (4 ld16 = 4 vm events)
#define STG(k0, b) do { \
    ld16(Ag + (size_t)(k0),        Asl + (b) * 8192); \
    ld16(Ag + (size_t)(k0) + a128, Asl + (b) * 8192 + 4096); \
    ld16(Bg + (size_t)(k0),        Bsl + (b) * 8192); \
    ld16(Bg + (size_t)(k0) + b128, Bsl + (b) * 8192 + 4096); \
} while (0)

template <int EPI>
__global__ __launch_bounds__(512, 2) void gemm_bt_k(
    const u16* __restrict__ A, const u16* __restrict__ B, void* __restrict__ Cout,
    const float* __restrict__ bias, const u16* __restrict__ addp16,
    int K, int lda, int ldb, int ldc)
{
    __shared__ __align__(16) u16 As[2 * BM * 32];   // 32 KiB (2 bufs)
    __shared__ __align__(16) u16 Bs[2 * BN * 32];   // 32 KiB
    const int tid = threadIdx.x;

    // XCD-aware swizzle: blocks with id%8==c (one XCD) cover a CONTIGUOUS
    // m-band x all n-tiles -> per-XCD A footprint drops 8x (L2-resident).
    int m0, n0;
    {
        const int id = blockIdx.y * gridDim.x + blockIdx.x;
        const int nb = gridDim.x * gridDim.y;
        if ((nb & 7) == 0) {
            const int per = nb >> 3;
            const int t = (id & 7) * per + (id >> 3);
            n0 = (t % gridDim.x) * BN;
            m0 = (t / gridDim.x) * BM;
        } else {
            n0 = blockIdx.x * BN;
            m0 = blockIdx.y * BM;
        }
    }

    const int wid = tid >> 6, l = tid & 63;
    const int wm = (wid >> 2) << 7;        // 0 or 128
    const int wn = (wid & 3) << 6;         // 0,64,128,192
    const int tm = l & 15, quad = l >> 4;
    // read-side swizzled chunk offset (u16 elems) — constant per lane
    const int cx = (quad ^ ((tm >> 1) & 3)) << 3;

    f32x4 acc[8][4] = {};

    // staging: 4 lanes/row (64B rows), 128 rows/round, 2 rounds per matrix
    const int srow = tid >> 2;
    const int scol = ((tid & 3) ^ ((tid >> 3) & 3)) << 3;  // pre-swizzled global chunk
    const u16* Ag = A + (size_t)(m0 + srow) * lda + scol;
    const u16* Bg = B + (size_t)(n0 + srow) * ldb + scol;
    u16* Asl = As + tid * 8;
    u16* Bsl = Bs + tid * 8;
    const size_t a128 = (size_t)128 * lda, b128 = (size_t)128 * ldb;

    const u16* Ard = As + (wm + tm) * 32 + cx;
    const u16* Brd = Bs + (wn + tm) * 32 + cx;

    const int ntk = K >> 5;   // K-tiles of 32 (>= 32 here)

    // prologue: tile0 -> buf0, tile1 -> buf1; wait tile0 only
    STG(0, 0);
    STG(32, 1);
    WAIT_VM4();
    BARRIER();

    for (int t = 0; t < ntk; ++t) {
        const int buf = t & 1;
        const int kf = ((t + 2 < ntk) ? (t + 2) : (ntk - 1)) << 5;  // tail restage: dead store
        const u16* Ab = Ard + buf * 8192;
        const u16* Bb = Brd + buf * 8192;

        bf16x8 af[8], bfr[4];
#pragma unroll
        for (int i = 0; i < 8; ++i)
            af[i] = *(const bf16x8*)(const void*)(Ab + i * 512);
#pragma unroll
        for (int j = 0; j < 4; ++j)
            bfr[j] = *(const bf16x8*)(const void*)(Bb + j * 512);
        WAIT_LGKM0();    // reads in regs -> buf(t) dead for this wave
        BARRIER();       // ... for ALL waves -> safe to overwrite
        STG(kf, buf);    // stage tile t+2 into buf(t)
        __builtin_amdgcn_s_setprio(1);
#pragma unroll
        for (int i = 0; i < 8; ++i)
#pragma unroll
            for (int j = 0; j < 4; ++j)
                acc[i][j] = MFMA16(af[i], bfr[j], acc[i][j], 0, 0, 0);
        __builtin_amdgcn_s_setprio(0);
        WAIT_VM4();      // own t+1 loads landed; t+2's 4 remain in flight
        BARRIER();       // all waves' t+1 loads landed -> next iter reads buf(t+1)
    }
    WAIT_VM0();          // drain tail stages

    // C/D layout: col=lane&15, row=quad*4+reg (m89/m91-verified)
#pragma unroll
    for (int i = 0; i < 8; ++i) {
        const int gmb = m0 + wm + i * 16 + (quad << 2);
#pragma unroll
        for (int j = 0; j < 4; ++j) {
            const int gn = n0 + wn + j * 16 + tm;
            float bv = 0.f;
            if (EPI == EPI_BIAS_BF16 || EPI == EPI_BIAS_RELU_BF16 || EPI == EPI_BIAS_ADDB_F32)
                bv = bias[gn];
#pragma unroll
            for (int r = 0; r < 4; ++r) {
                size_t off = (size_t)(gmb + r) * ldc + gn;
                float v = acc[i][j][r] + bv;
                if (EPI == EPI_BIAS_ADDB_F32) v += b2f(addp16[off]);
                if (EPI == EPI_ADD_F32)       v += ((const float*)Cout)[off];
                if (EPI == EPI_BIAS_RELU_BF16) v = fmaxf(v, 0.f);
                if (EPI == EPI_BF16 || EPI == EPI_BIAS_BF16 || EPI == EPI_BIAS_RELU_BF16)
                    ((u16*)Cout)[off] = f2b(v);
                else
                    ((float*)Cout)[off] = v;
            }
        }
    }
}

// ---------------- LayerNorm bf16 -> bf16 (may be in-place) ----------------
__global__ void ln_bf16_k(const u16* __restrict__ src, u16* __restrict__ dst,
                          const float* __restrict__ g, const float* __restrict__ be) {
    __shared__ float red[8];
    const int t = blockIdx.x, tid = threadIdx.x;
    ushort4 h = ((const ushort4*)(src + (size_t)t * DD))[tid];
    float4 v = { b2f(h.x), b2f(h.y), b2f(h.z), b2f(h.w) };
    float s  = v.x + v.y + v.z + v.w;
    float ss = v.x * v.x + v.y * v.y + v.z * v.z + v.w * v.w;
    block_red2(s, ss, red, tid);
    float mean = s * (1.f / 1024.f);
    float inv  = 1.0f / sqrtf(ss * (1.f / 1024.f) - mean * mean + 1e-5f);
    float4 gv = ((const float4*)g)[tid];
    float4 bv = ((const float4*)be)[tid];
    ushort4 o;
    o.x = f2b((v.x - mean) * inv * gv.x + bv.x);
    o.y = f2b((v.y - mean) * inv * gv.y + bv.y);
    o.z = f2b((v.z - mean) * inv * gv.z + bv.z);
    o.w = f2b((v.w - mean) * inv * gv.w + bv.w);
    ((ushort4*)(dst + (size_t)t * DD))[tid] = o;
}

// ---------------- final LN in place on d_out (f32) ----------------
__global__ void ln_out_k(float* __restrict__ io, const float* __restrict__ g,
                         const float* __restrict__ be) {
    __shared__ float red[8];
    const int t = blockIdx.x, tid = threadIdx.x;
    float4 v = ((const float4*)(io + (size_t)t * DD))[tid];
    float s  = v.x + v.y + v.z + v.w;
    float ss = v.x * v.x + v.y * v.y + v.z * v.z + v.w * v.w;
    block_red2(s, ss, red, tid);
    float mean = s * (1.f / 1024.f);
    float inv  = 1.0f / sqrtf(ss * (1.f / 1024.f) - mean * mean + 1e-5f);
    float4 gv = ((const float4*)g)[tid];
    float4 bv = ((const float4*)be)[tid];
    float4 o;
    o.x = (v.x - mean) * inv * gv.x + bv.x;
    o.y = (v.y - mean) * inv * gv.y + bv.y;
    o.z = (v.z - mean) * inv * gv.z + bv.z;
    o.w = (v.w - mean) * inv * gv.w + bv.w;
    ((float4*)(io + (size_t)t * DD))[tid] = o;
}

// ---------------- pw1: Sf[b] += Kf .* Xf  (packed spectra) ----------------
#define PW1_TOK 16
__global__ void pw1_k(const u16* __restrict__ FTx, const u16* __restrict__ FTk,
                      float* __restrict__ Sf) {
    const int tid = threadIdx.x;
    const int t0 = blockIdx.x * PW1_TOK;
    const int b = t0 >> 12;
    float a0 = 0.f;
    float ar1 = 0.f, ai1 = 0.f;
    float ar2 = 0.f, ai2 = 0.f;
    const int f1 = tid + 1, f2 = tid + 257;
    for (int it = 0; it < PW1_TOK; ++it) {
        const size_t ro = (size_t)(t0 + it) * DD;
        const u16* rx = FTx + ro;
        const u16* rk = FTk + ro;
        if (tid == 0) a0 += b2f(rk[0]) * b2f(rx[0]);
        {
            float xr = b2f(rx[2 * f1 - 1]), xi = b2f(rx[2 * f1]);
            float kr = b2f(rk[2 * f1 - 1]), ki = b2f(rk[2 * f1]);
            ar1 += kr * xr - ki * xi;
            ai1 += kr * xi + ki * xr;
        }
        if (f2 < 512) {
            float xr = b2f(rx[2 * f2 - 1]), xi = b2f(rx[2 * f2]);
            float kr = b2f(rk[2 * f2 - 1]), ki = b2f(rk[2 * f2]);
            ar2 += kr * xr - ki * xi;
            ai2 += kr * xi + ki * xr;
        } else {
            ar2 += b2f(rk[1023]) * b2f(rx[1023]);
        }
    }
    float* sb = Sf + (size_t)b * DD;
    if (tid == 0) atomicAdd(&sb[0], a0);
    atomicAdd(&sb[2 * f1 - 1], ar1);
    atomicAdd(&sb[2 * f1],     ai1);
    if (f2 < 512) {
        atomicAdd(&sb[2 * f2 - 1], ar2);
        atomicAdd(&sb[2 * f2],     ai2);
    } else {
        atomicAdd(&sb[1023], ar2);
    }
}

// ---------------- pw2: G = Xf + Kf.*Xf + Sf.*conj(Qf), in-place over FTx ----------------
__global__ void pw2_k(u16* __restrict__ FTx, const u16* __restrict__ FTk,
                      const u16* __restrict__ FTq, const float* __restrict__ Sf) {
    const int t = blockIdx.x, tid = threadIdx.x;
    const int b = t >> 12;
    const size_t ro = (size_t)t * DD;
    u16* rx = FTx + ro;
    const u16* rk = FTk + ro;
    const u16* rq = FTq + ro;
    const float* sb = Sf + (size_t)b * DD;
    const int f1 = tid + 1, f2 = tid + 257;
    if (tid == 0) {
        float x = b2f(rx[0]), k = b2f(rk[0]), q = b2f(rq[0]);
        rx[0] = f2b(x + k * x + sb[0] * q);
    }
    {
        float xr = b2f(rx[2 * f1 - 1]), xi = b2f(rx[2 * f1]);
        float kr = b2f(rk[2 * f1 - 1]), ki = b2f(rk[2 * f1]);
        float qr = b2f(rq[2 * f1 - 1]), qi = b2f(rq[2 * f1]);
        float sr = sb[2 * f1 - 1], si = sb[2 * f1];
        rx[2 * f1 - 1] = f2b(xr + (kr * xr - ki * xi) + (sr * qr + si * qi));
        rx[2 * f1]     = f2b(xi + (kr * xi + ki * xr) + (si * qr - sr * qi));
    }
    if (f2 < 512) {
        float xr = b2f(rx[2 * f2 - 1]), xi = b2f(rx[2 * f2]);
        float kr = b2f(rk[2 * f2 - 1]), ki = b2f(rk[2 * f2]);
        float qr = b2f(rq[2 * f2 - 1]), qi = b2f(rq[2 * f2]);
        float sr = sb[2 * f2 - 1], si = sb[2 * f2];
        rx[2 * f2 - 1] = f2b(xr + (kr * xr - ki * xi) + (sr * qr + si * qi));
        rx[2 * f2]     = f2b(xi + (kr * xi + ki * xr) + (si * qr - sr * qi));
    } else {
        float x = b2f(rx[1023]), k = b2f(rk[1023]), q = b2f(rq[1023]);
        rx[1023] = f2b(x + k * x + sb[1023] * q);
    }
}

// ---------------- launch ----------------
extern "C" void kernel_launch(void* const* d_in, const int* in_sizes, int n_in,
                              void* d_out, int out_size, void* d_ws, size_t ws_size,
                              hipStream_t stream) {
    const float* x     = (const float*)d_in[0];
    const float* Wq    = (const float*)d_in[1];
    const float* bq    = (const float*)d_in[2];
    const float* gq    = (const float*)d_in[3];
    const float* betaq = (const float*)d_in[4];
    const float* Wk    = (const float*)d_in[5];
    const float* bk    = (const float*)d_in[6];
    const float* gk    = (const float*)d_in[7];
    const float* betak = (const float*)d_in[8];
    const float* g0    = (const float*)d_in[9];
    const float* beta0 = (const float*)d_in[10];
    const float* W1    = (const float*)d_in[11];
    const float* b1    = (const float*)d_in[12];
    const float* W2    = (const float*)d_in[13];
    const float* b2    = (const float*)d_in[14];
    const float* g1    = (const float*)d_in[15];
    const float* beta1 = (const float*)d_in[16];

    char* ws = (char*)d_ws;
    u16* S1 = (u16*)(ws + S1O);   // xb16 -> FTk -> x1b
    u16* S2 = (u16*)(ws + S2O);   // qb -> T
    u16* S3 = (u16*)(ws + S3O);   // kb -> FTq -> H chunk
    u16* S4 = (u16*)(ws + S4O);   // FTx -> G -> H chunk
    u16* wq16 = (u16*)(ws + O_WQ);
    u16* wk16 = (u16*)(ws + O_WK);
    u16* w116 = (u16*)(ws + O_W1);
    u16* w216 = (u16*)(ws + O_W2);
    u16* fwdP = (u16*)(ws + O_FWD);
    u16* invP = (u16*)(ws + O_INV);
    float* Sf = (float*)(ws + O_SF);
    float* out = (float*)d_out;

    // consts
    zero_sf_k<<<16, 256, 0, stream>>>(Sf);
    cast_f32_bf16_k<<<16384, 256, 0, stream>>>(x, S1, 4194304);
    cast_f32_bf16_k<<<1024, 256, 0, stream>>>(Wq, wq16, 262144);
    cast_f32_bf16_k<<<1024, 256, 0, stream>>>(Wk, wk16, 262144);
    cast_f32_bf16_k<<<4096, 256, 0, stream>>>(W1, w116, 1048576);
    cast_f32_bf16_k<<<4096, 256, 0, stream>>>(W2, w216, 1048576);
    gen_fwd_k<<<4096, 256, 0, stream>>>(fwdP);
    gen_inv_k<<<4096, 256, 0, stream>>>(invP);

    // projections (bias in epilogue, bf16 out), then LN in-place
    gemm_bt_k<EPI_BIAS_BF16><<<dim3(4, 64), 512, 0, stream>>>(S1, wq16, S2, bq, nullptr, 1024, 1024, 1024, 1024);
    gemm_bt_k<EPI_BIAS_BF16><<<dim3(4, 64), 512, 0, stream>>>(S1, wk16, S3, bk, nullptr, 1024, 1024, 1024, 1024);
    ln_bf16_k<<<NT, 256, 0, stream>>>(S2, S2, gq, betaq);
    ln_bf16_k<<<NT, 256, 0, stream>>>(S3, S3, gk, betak);

    // forward DFTs (packed spectra)
    gemm_bt_k<EPI_BF16><<<dim3(4, 64), 512, 0, stream>>>(S1, fwdP, S4, nullptr, nullptr, 1024, 1024, 1024, 1024); // FTx
    gemm_bt_k<EPI_BF16><<<dim3(4, 64), 512, 0, stream>>>(S3, fwdP, S1, nullptr, nullptr, 1024, 1024, 1024, 1024); // FTk
    gemm_bt_k<EPI_BF16><<<dim3(4, 64), 512, 0, stream>>>(S2, fwdP, S3, nullptr, nullptr, 1024, 1024, 1024, 1024); // FTq

    // freq-domain pointwise
    pw1_k<<<NT / PW1_TOK, 256, 0, stream>>>(S4, S1, Sf);
    pw2_k<<<NT, 256, 0, stream>>>(S4, S1, S3, Sf);   // G in-place over FTx (S4)

    // inverse DFT: T = G @ Inv^T (bf16)
    gemm_bt_k<EPI_BF16><<<dim3(4, 64), 512, 0, stream>>>(S4, invP, S2, nullptr, nullptr, 1024, 1024, 1024, 1024);

    // x1 = LN(T) -> bf16
    ln_bf16_k<<<NT, 256, 0, stream>>>(S2, S1, g0, beta0);

    // FFN in two F-chunks of 2048; H chunk lives in S3..S4 (64MB)
    gemm_bt_k<EPI_BIAS_RELU_BF16><<<dim3(8, 64), 512, 0, stream>>>(S1, w116, S3, b1, nullptr, 1024, 1024, 1024, 2048);
    gemm_bt_k<EPI_BIAS_ADDB_F32><<<dim3(4, 64), 512, 0, stream>>>(S3, w216, out, b2, S1, 2048, 2048, 4096, 1024);
    gemm_bt_k<EPI_BIAS_RELU_BF16><<<dim3(8, 64), 512, 0, stream>>>(S1, w116 + (size_t)2048 * 1024, S3, b1 + 2048, nullptr, 1024, 1024, 1024, 2048);
    gemm_bt_k<EPI_ADD_F32><<<dim3(4, 64), 512, 0, stream>>>(S3, w216 + 2048, out, nullptr, nullptr, 2048, 2048, 4096, 1024);

    // final LN in place
    ln_out_k<<<NT, 256, 0, stream>>>(out, g1, beta1);

    (void)in_sizes; (void)n_in; (void)out_size; (void)ws_size;
}